// Round 11
// baseline (421.678 us; speedup 1.0000x reference)
//
#include <hip/hip_runtime.h>
#include <math.h>

#define NP 11
#define NN 8    // nodes per block (512 threads, 8 waves)

__device__ __constant__ int g_l1[NP]   = {0,1,2,0,1,1,2,0,1,2,2};
__device__ __constant__ int g_l2[NP]   = {0,1,2,1,0,2,1,2,1,0,2};
__device__ __constant__ int g_l3[NP]   = {0,0,0,1,1,1,1,2,2,2,2};
__device__ __constant__ int g_coff[NP] = {0,1,10,35,44,53,98,143,168,213,238};

typedef _Float16 half8 __attribute__((ext_vector_type(8)));
typedef _Float16 h2 __attribute__((ext_vector_type(2)));
typedef float f32x4 __attribute__((ext_vector_type(4)));

// ---------------- helpers ----------------
__device__ __forceinline__ float bfu(unsigned int v){ return __uint_as_float(v<<16); }
__device__ __forceinline__ unsigned int rne16(float f){
  unsigned int ui=__float_as_uint(f);
  return (ui+0x7fffu+((ui>>16)&1u))>>16;
}
__device__ __forceinline__ unsigned short h16(float f){
  _Float16 h=(_Float16)f;
  return __builtin_bit_cast(unsigned short,h);
}
__device__ __forceinline__ float hf(unsigned short s){
  return (float)__builtin_bit_cast(_Float16,s);
}

// ---------------- Wigner-3j pieces (exact replica of reference, fp64) ----------------
__device__ double dfact(int n){ double r=1.0; for(int i=2;i<=n;++i) r*=(double)i; return r; }

__device__ double su2_cg(int j1,int m1,int j2,int m2,int j3,int m3){
  if(m1+m2!=m3) return 0.0;
  int vmin=-j1+j2+m3; if(-j1+m1>vmin) vmin=-j1+m1; if(vmin<0) vmin=0;
  int vmax=j2+j3+m1; int t=j3-j1+j2; if(t<vmax) vmax=t; t=j3+m3; if(t<vmax) vmax=t;
  double C = sqrt((double)(2*j3+1)*dfact(j3+j1-j2)*dfact(j3-j1+j2)*dfact(j1+j2-j3)
      *dfact(j3+m3)*dfact(j3-m3)
      /(dfact(j1+j2+j3+1)*dfact(j1-m1)*dfact(j1+m1)*dfact(j2-m2)*dfact(j2+m2)));
  double S=0.0;
  for(int v=vmin;v<=vmax;++v){
    double sg = ((v+j2+m2)&1)? -1.0:1.0;
    S += sg*dfact(j2+j3+m1-v)*dfact(j1-m1+v)
        /(dfact(v)*dfact(j3-j1+j2-v)*dfact(j3+m3-v)*dfact(v+j1-j2-m3));
  }
  return C*S;
}

__device__ void qelem(int l,int r,int c,double &re,double &im){
  int m=r-l; double a=0.0,b=0.0; const double s=0.70710678118654752440;
  if(m<0){ if(c==l-m) a=s; else if(c==l+m) b=-s; }
  else if(m==0){ if(c==l) a=1.0; }
  else { double sg=(m&1)?-1.0:1.0; if(c==l+m) a=sg*s; else if(c==l-m) b=sg*s; }
  if(l==1){ double tt=a; a=b; b=-tt; }
  else if(l==2){ a=-a; b=-b; }
  re=a; im=b;
}

__device__ int probe_f32(const unsigned short* __restrict__ p, int nelem, int* scnt){
  if(threadIdx.x==0) *scnt=0;
  __syncthreads();
  int M = nelem < 4096 ? nelem : 4096;
  int c=0;
  for(int t=threadIdx.x;t<M;t+=blockDim.x){
    unsigned e=((unsigned)p[t]>>7)&0xFFu;
    if(e!=0u && (e<0x70u || e>0x8Eu)) ++c;
  }
  atomicAdd(scnt,c);
  __syncthreads();
  return (*scnt*8 > M) ? 1 : 0;
}

// ---------------- ONE prep kernel ----------------
// wpre[(p*3+tp)*2240 + w*140 + c] = pack_fp16(W[2c][w], W[2c+1][w])   (col c=u*8+vp)
__global__ void prep(const unsigned short* __restrict__ x,
                     const unsigned short* __restrict__ wq,
                     const unsigned short* __restrict__ wk,
                     const unsigned short* __restrict__ wv,
                     const unsigned short* __restrict__ wd,
                     int nx,int nw,int nd,
                     float* __restrict__ c3j, unsigned int* __restrict__ cgh,
                     unsigned int* __restrict__ wpre){
  const int p=blockIdx.x, tp=blockIdx.y;
  __shared__ double cg[125];
  __shared__ double outv[125];
  __shared__ double nrm;
  __shared__ int scnt;

  const unsigned short* ww=(tp==0)?wq:((tp==1)?wk:wv);
  const int f32 = probe_f32(ww,nw,&scnt);

  {
    unsigned int* dst=wpre+(size_t)(p*3+tp)*2240;
    for(int t=threadIdx.x;t<2048;t+=256){
      int w=t>>7, c=t&127;
      int i0=c*32+w, i1=i0+16;
      float f0,f1;
      if(f32){
        const float* wf=(const float*)ww+(size_t)p*4096;
        f0=wf[i0]; f1=wf[i1];
      }else{
        const unsigned short* wsp=ww+(size_t)p*4096;
        f0=bfu(wsp[i0]); f1=bfu(wsp[i1]);
      }
      dst[w*140+c]=(unsigned int)h16(f0)|((unsigned int)h16(f1)<<16);
    }
  }

  if(tp==0){
    int l1=g_l1[p], l2=g_l2[p], l3=g_l3[p];
    int d1=2*l1+1, d2=2*l2+1, d3=2*l3+1;
    int tot=d1*d2*d3;
    for(int t=threadIdx.x;t<tot;t+=256){
      int i=t/(d2*d3), k=(t/d3)%d2, n=t%d3;
      cg[t]=su2_cg(l1,i-l1,l2,k-l2,l3,n-l3);
    }
    __syncthreads();
    for(int t=threadIdx.x;t<tot;t+=256){
      int a=t/(d2*d3), b=(t/d3)%d2, c=t%d3;
      double sre=0.0;
      for(int i=0;i<d1;++i){ double q1r,q1i; qelem(l1,i,a,q1r,q1i);
        for(int k=0;k<d2;++k){ double q2r,q2i; qelem(l2,k,b,q2r,q2i);
          double pr=q1r*q2r-q1i*q2i, pi=q1r*q2i+q1i*q2r;
          for(int n=0;n<d3;++n){ double q3r,q3i; qelem(l3,n,c,q3r,q3i);
            sre += (pr*q3r + pi*q3i) * cg[(i*d2+k)*d3+n];
          }
        }
      }
      outv[t]=sre;
    }
    __syncthreads();
    if(threadIdx.x==0){
      double s=0.0; for(int t=0;t<tot;++t) s+=outv[t]*outv[t];
      nrm=sqrt(s);
    }
    __syncthreads();
    const float scl_[3]={0.03608439182435161f,0.05412658773652741f,0.06987712429686843f};
    float s=scl_[l3];
    for(int t=threadIdx.x;t<tot;t+=256){
      float val=(float)(outv[t]/nrm);
      c3j[g_coff[p]+t]=val;
      unsigned int h=(unsigned int)h16(val*s);
      cgh[g_coff[p]+t]=h|(h<<16);
    }
  }

  if(p==0 && tp==0){
    int xf=probe_f32(x,nx,&scnt);
    if(threadIdx.x==0) c3j[363]=(float)xf;
    int df=probe_f32(wd,nd,&scnt);
    if(threadIdx.x==0) c3j[367]=(float)df;
  }
}

// ---------------- LDS layout (dwords), single block ----------------
#define L_AU   0        // 40*140 = 5600 (stage2 reads up to row 47 -> spills into L_SO, harmless)
#define L_SO   5600     // 8*224 dwords of fp16 pairs (q|k|v per node, 448 halves); also fp32 x scratch
#define L_XP   7392     // 8*76 (v,v+1)-pair packs
#define L_XD   8000     // 8*148 (x,x) dup packs
#define L_WD   9184     // 384 dwords = 768 fp16 dot-weights
#define L_CG   9568     // 363 packed scale*C fp16 pairs
#define L_TOT  9932

// ---------------- fused stage 1, all-packed fp16, x images in registers ----------------
template<int D1,int D2,int D3>
__device__ __forceinline__ void fusedAB(const h2* __restrict__ x2p,
                                        const h2* __restrict__ x1a,
                                        const h2* __restrict__ x1b,
                                        const unsigned int* __restrict__ cgp,
                                        unsigned int* __restrict__ sAu,
                                        int wave, int lane, int nvalid){
  const int nn=lane>>3, vp=lane&7;
  if(nn>=nvalid) return;
  const int u0=wave*2;
  h2 acc0[D3],acc1[D3];
  #pragma unroll
  for(int k=0;k<D3;++k){ acc0[k]=(h2){(_Float16)0.f,(_Float16)0.f}; acc1[k]=acc0[k]; }
  #pragma unroll
  for(int i=0;i<D1;++i){
    #pragma unroll
    for(int k=0;k<D3;++k){
      h2 ar=(h2){(_Float16)0.f,(_Float16)0.f};
      #pragma unroll
      for(int j=0;j<D2;++j)
        ar+=__builtin_bit_cast(h2,cgp[(i*D2+j)*D3+k])*x2p[j];
      acc0[k]+=x1a[i]*ar;
      acc1[k]+=x1b[i]*ar;
    }
  }
  #pragma unroll
  for(int k=0;k<D3;++k){
    sAu[(k*8+nn)*140+u0*8+vp]   =__builtin_bit_cast(unsigned int,acc0[k]);
    sAu[(k*8+nn)*140+u0*8+vp+8] =__builtin_bit_cast(unsigned int,acc1[k]);
  }
}

// ---------------- stage 2: MFMA, A from LDS, B loaded inline (short liveness) ----------------
template<int L3>
__device__ __forceinline__ void stage2_acc(const unsigned int* __restrict__ sAu,
                                           const unsigned int* __restrict__ wp_path,
                                           f32x4& a0, f32x4& a1,
                                           int n16, int quad, int wave){
  constexpr int P=(L3+1)*3;
  if(wave<P){
    int tp=wave%3, Mt=wave/3;
    const unsigned int* ap=sAu+(Mt*16+n16)*140+quad*4;
    const uint4* bp=(const uint4*)(wp_path+tp*2240+n16*140+quad*4);
    uint4 b[8];
    #pragma unroll
    for(int ks=0;ks<8;++ks) b[ks]=bp[ks*4];
    f32x4 a=a0;
    #pragma unroll
    for(int ks=0;ks<8;++ks)
      a=__builtin_amdgcn_mfma_f32_16x16x32_f16(
          *reinterpret_cast<const half8*>(ap+ks*16),
          __builtin_bit_cast(half8,b[ks]),a,0,0,0);
    a0=a;
  }
  if(L3==2 && wave==0){           // pid 8: tp=2, Mt=2
    const unsigned int* ap=sAu+(2*16+n16)*140+quad*4;
    const uint4* bp=(const uint4*)(wp_path+2*2240+n16*140+quad*4);
    uint4 b2[8];
    #pragma unroll
    for(int ks=0;ks<8;++ks) b2[ks]=bp[ks*4];
    f32x4 a=a1;
    #pragma unroll
    for(int ks=0;ks<8;++ks)
      a=__builtin_amdgcn_mfma_f32_16x16x32_f16(
          *reinterpret_cast<const half8*>(ap+ks*16),
          __builtin_bit_cast(half8,b2[ks]),a,0,0,0);
    a1=a;
  }
}

template<int L3>
__device__ __forceinline__ void stage2_out(const f32x4& a0, const f32x4& a1,
                                           unsigned short* __restrict__ sOh,
                                           int n16, int quad, int wave){
  constexpr int D3=2*L3+1;
  constexpr int OO=(L3==0)?0:((L3==1)?16:64);
  constexpr int P=(L3+1)*3;
  if(wave<P){
    int tp=wave%3, Mt=wave/3;
    #pragma unroll
    for(int reg=0;reg<4;++reg){
      int row=Mt*16+quad*4+reg;
      int k=row>>3, node=row&7;
      if(k<D3) sOh[node*448+tp*144+OO+n16*D3+k]=h16(a0[reg]);
    }
  }
  if(L3==2 && wave==0){
    #pragma unroll
    for(int reg=0;reg<4;++reg){
      int row=32+quad*4+reg;
      int k=row>>3, node=row&7;
      if(k<D3) sOh[node*448+2*144+OO+n16*D3+k]=h16(a1[reg]);
    }
  }
}

__global__ __launch_bounds__(512,6) void tfn_main(
    const unsigned short* __restrict__ xin,
    const unsigned int* __restrict__ wpre,
    const unsigned int* __restrict__ cgh,
    const unsigned short* __restrict__ wd,
    const float* __restrict__ c3j,
    unsigned short* __restrict__ outp, int N)
{
  __shared__ __align__(16) unsigned int lds[L_TOT];

  const int tid=threadIdx.x;
  const int wave=tid>>6, lane=tid&63;
  const int n16=lane&15, quad=lane>>4;
  const int node0=blockIdx.x*NN;
  const int nvalid=(N-node0)<NN?(N-node0):NN;

  const int xf32 = c3j[363]!=0.0f;
  const int df32 = c3j[367]!=0.0f;

  unsigned int* sAu=lds+L_AU;
  unsigned short* sOh=(unsigned short*)(lds+L_SO);
  unsigned short* sWdh=(unsigned short*)(lds+L_WD);

  // ---- stage x into fp32 scratch (sO region; consumed before first stage2_out) ----
  float* scratch=(float*)(lds+L_SO);
  if(!xf32){
    for(int t=tid;t<NN*36;t+=512){
      int nn=t/36, w4=t%36;
      if(nn<nvalid){
        uint2 u=((const uint2*)(xin+(size_t)(node0+nn)*144))[w4];
        float* dst=&scratch[nn*144+w4*4];
        dst[0]=bfu(u.x&0xffffu); dst[1]=bfu(u.x>>16);
        dst[2]=bfu(u.y&0xffffu); dst[3]=bfu(u.y>>16);
      }
    }
  }else{
    const float* xf=(const float*)xin;
    for(int t=tid;t<NN*144;t+=512){
      int nn=t/144, f=t%144;
      if(nn<nvalid) scratch[nn*144+f]=xf[(size_t)(node0+nn)*144+f];
    }
  }
  if(!df32){ for(int t=tid;t<768;t+=512) sWdh[t]=(unsigned short)h16(bfu((unsigned int)wd[t])); }
  else     { const float* wdf=(const float*)wd; for(int t=tid;t<768;t+=512) sWdh[t]=(unsigned short)h16(wdf[t]); }
  for(int t=tid;t<363;t+=512) lds[L_CG+t]=cgh[t];
  __syncthreads();

  // ---- build packed fp16 x images ----
  for(int t=tid;t<NN*144;t+=512){
    int nn=t/144, f=t-nn*144;
    unsigned int h=(unsigned int)h16(scratch[t]);
    lds[L_XD+nn*148+f]=h|(h<<16);
  }
  for(int t=tid;t<NN*72;t+=512){
    int nn=t/72, g=t-nn*72;
    int fa,fb;
    if(g<8){ fa=2*g; fb=fa+1; }
    else if(g<32){ int gg=g-8; int vp=gg/3, j=gg-3*vp; fa=16+(2*vp)*3+j; fb=fa+3; }
    else { int gg=g-32; int vp=gg/5, j=gg-5*vp; fa=64+(2*vp)*5+j; fb=fa+5; }
    lds[L_XP+nn*76+g]=(unsigned int)h16(scratch[nn*144+fa])|((unsigned int)h16(scratch[nn*144+fb])<<16);
  }
  __syncthreads();

  // ---- hoist this lane's x images into registers (LDS aliasing blocks compiler from doing this) ----
  const int nn_=lane>>3, vp_=lane&7, u0_=wave*2;
  h2 xp1[1],xp3[3],xp5[5];
  h2 xa1[1],xb1[1],xa3[3],xb3[3],xa5[5],xb5[5];
  {
    const unsigned int* xp=lds+L_XP+nn_*76;
    xp1[0]=__builtin_bit_cast(h2,xp[vp_]);
    #pragma unroll
    for(int j=0;j<3;++j) xp3[j]=__builtin_bit_cast(h2,xp[8+vp_*3+j]);
    #pragma unroll
    for(int j=0;j<5;++j) xp5[j]=__builtin_bit_cast(h2,xp[32+vp_*5+j]);
    const unsigned int* xd=lds+L_XD+nn_*148;
    xa1[0]=__builtin_bit_cast(h2,xd[u0_]);
    xb1[0]=__builtin_bit_cast(h2,xd[u0_+1]);
    #pragma unroll
    for(int i=0;i<3;++i){
      xa3[i]=__builtin_bit_cast(h2,xd[16+u0_*3+i]);
      xb3[i]=__builtin_bit_cast(h2,xd[16+(u0_+1)*3+i]);
    }
    #pragma unroll
    for(int i=0;i<5;++i){
      xa5[i]=__builtin_bit_cast(h2,xd[64+u0_*5+i]);
      xb5[i]=__builtin_bit_cast(h2,xd[64+(u0_+1)*5+i]);
    }
  }
  #define X2S(D2_) ((D2_)==1?xp1:((D2_)==3?xp3:xp5))
  #define X1A(D1_) ((D1_)==1?xa1:((D1_)==3?xa3:xa5))
  #define X1B(D1_) ((D1_)==1?xb1:((D1_)==3?xb3:xb5))

  // one path step: fusedAB, barrier, MFMA (inline B loads), barrier
  #define PATH_STEP(P_,D1_,D2_,D3_) { \
    fusedAB<D1_,D2_,D3_>(X2S(D2_),X1A(D1_),X1B(D1_),lds+L_CG+g_coff[P_],sAu,wave,lane,nvalid); \
    __syncthreads(); \
    stage2_acc<(D3_-1)/2>(sAu,wpre+(size_t)P_*6720,a0,a1,n16,quad,wave); \
    __syncthreads(); }

  { // group l3=0: paths 0,1,2
    f32x4 a0={0.f,0.f,0.f,0.f}, a1={0.f,0.f,0.f,0.f};
    PATH_STEP(0,1,1,1)
    PATH_STEP(1,3,3,1)
    PATH_STEP(2,5,5,1)
    stage2_out<0>(a0,a1,sOh,n16,quad,wave);
  }
  { // group l3=1: paths 3,4,5,6
    f32x4 a0={0.f,0.f,0.f,0.f}, a1={0.f,0.f,0.f,0.f};
    PATH_STEP(3,1,3,3)
    PATH_STEP(4,3,1,3)
    PATH_STEP(5,3,5,3)
    PATH_STEP(6,5,3,3)
    stage2_out<1>(a0,a1,sOh,n16,quad,wave);
  }
  { // group l3=2: paths 7,8,9,10
    f32x4 a0={0.f,0.f,0.f,0.f}, a1={0.f,0.f,0.f,0.f};
    PATH_STEP(7,1,5,5)
    PATH_STEP(8,3,3,5)
    PATH_STEP(9,5,1,5)
    PATH_STEP(10,5,5,5)
    stage2_out<2>(a0,a1,sOh,n16,quad,wave);
  }
  #undef PATH_STEP
  __syncthreads();

  // ---- epilogue: dot via C(l,l,0)=c_l*I; attention; elu; store ----
  {
    int node=wave;
    if(node<nvalid){
      const float c0=c3j[0], c1=c3j[1], c2=c3j[10];
      const unsigned short* qh=sOh+node*448;
      const unsigned short* kh=qh+144;
      const int v=lane&15, ug=lane>>4;
      float k0=hf(kh[v]);
      float k1[3],k2[5];
      #pragma unroll
      for(int j=0;j<3;++j) k1[j]=hf(kh[16+v*3+j]);
      #pragma unroll
      for(int m=0;m<5;++m) k2[m]=hf(kh[64+v*5+m]);
      float part=0.f;
      #pragma unroll
      for(int t=0;t<4;++t){
        int u=ug+4*t;
        float d0=hf(qh[u])*k0;
        float d1=0.f;
        #pragma unroll
        for(int j=0;j<3;++j) d1+=hf(qh[16+u*3+j])*k1[j];
        float d2=0.f;
        #pragma unroll
        for(int m=0;m<5;++m) d2+=hf(qh[64+u*5+m])*k2[m];
        part+=hf(sWdh[u*16+v])*(c0*d0)+hf(sWdh[256+u*16+v])*(c1*d1)+hf(sWdh[512+u*16+v])*(c2*d2);
      }
      #pragma unroll
      for(int off=1;off<64;off<<=1) part+=__shfl_xor(part,off,64);
      float dd=part*0.03608439182435161f;   // * sqrt(1/768)
      float ex=dd*(1.0f/12.0f);             // / sqrt(144)
      ex=fminf(fmaxf(ex,-80.f),80.f);
      float e=expf(ex);
      float attn=e/(e+1e-10f);
      const unsigned short* vh=qh+288;
      if(!xf32){
        unsigned short* ob=outp+(size_t)(node0+node)*144;
        for(int f=lane;f<144;f+=64){
          float val=attn*hf(vh[f]);
          float r=(val>0.f)?val:expm1f(val);
          ob[f]=(unsigned short)rne16(r);
        }
      }else{
        float* ob=(float*)outp+(size_t)(node0+node)*144;
        for(int f=lane;f<144;f+=64){
          float val=attn*hf(vh[f]);
          ob[f]=(val>0.f)?val:expm1f(val);
        }
      }
    }
  }
}

extern "C" void kernel_launch(void* const* d_in, const int* in_sizes, int n_in,
                              void* d_out, int out_size, void* d_ws, size_t ws_size,
                              hipStream_t stream){
  (void)n_in; (void)out_size; (void)ws_size;
  const unsigned short* x =(const unsigned short*)d_in[0];
  const unsigned short* wq=(const unsigned short*)d_in[4];
  const unsigned short* wk=(const unsigned short*)d_in[5];
  const unsigned short* wv=(const unsigned short*)d_in[6];
  const unsigned short* wd=(const unsigned short*)d_in[7];
  float* c3j=(float*)d_ws;                                 // [0..362] w3j, [363..367] flags
  unsigned int* cgh=(unsigned int*)d_ws+1024;              // packed scale*C fp16 pairs (363)
  unsigned int* wpre=(unsigned int*)d_ws+2048;             // 11*3*2240 packed fp16 W^T
  int N=in_sizes[0]/144;
  prep<<<dim3(NP,3),dim3(256),0,stream>>>(x,wq,wk,wv,wd,
      in_sizes[0],in_sizes[4],in_sizes[7],c3j,cgh,wpre);
  int nb=(N+NN-1)/NN;
  tfn_main<<<dim3(nb),dim3(512),0,stream>>>(x,wpre,cgh,wd,c3j,(unsigned short*)d_out,N);
}

// Round 12
// 354.295 us; speedup vs baseline: 1.1902x; 1.1902x over previous
//
#include <hip/hip_runtime.h>
#include <math.h>

#define NP 11
#define NN 8    // nodes per block (512 threads, 8 waves)

__device__ __constant__ int g_l1[NP]   = {0,1,2,0,1,1,2,0,1,2,2};
__device__ __constant__ int g_l2[NP]   = {0,1,2,1,0,2,1,2,1,0,2};
__device__ __constant__ int g_l3[NP]   = {0,0,0,1,1,1,1,2,2,2,2};
__device__ __constant__ int g_coff[NP] = {0,1,10,35,44,53,98,143,168,213,238};

typedef _Float16 half8 __attribute__((ext_vector_type(8)));
typedef _Float16 h2 __attribute__((ext_vector_type(2)));
typedef float f32x4 __attribute__((ext_vector_type(4)));

// ---------------- helpers ----------------
__device__ __forceinline__ float bfu(unsigned int v){ return __uint_as_float(v<<16); }
__device__ __forceinline__ unsigned int rne16(float f){
  unsigned int ui=__float_as_uint(f);
  return (ui+0x7fffu+((ui>>16)&1u))>>16;
}
__device__ __forceinline__ unsigned short h16(float f){
  _Float16 h=(_Float16)f;
  return __builtin_bit_cast(unsigned short,h);
}

// ---------------- Wigner-3j pieces (exact replica of reference, fp64) ----------------
__device__ double dfact(int n){ double r=1.0; for(int i=2;i<=n;++i) r*=(double)i; return r; }

__device__ double su2_cg(int j1,int m1,int j2,int m2,int j3,int m3){
  if(m1+m2!=m3) return 0.0;
  int vmin=-j1+j2+m3; if(-j1+m1>vmin) vmin=-j1+m1; if(vmin<0) vmin=0;
  int vmax=j2+j3+m1; int t=j3-j1+j2; if(t<vmax) vmax=t; t=j3+m3; if(t<vmax) vmax=t;
  double C = sqrt((double)(2*j3+1)*dfact(j3+j1-j2)*dfact(j3-j1+j2)*dfact(j1+j2-j3)
      *dfact(j3+m3)*dfact(j3-m3)
      /(dfact(j1+j2+j3+1)*dfact(j1-m1)*dfact(j1+m1)*dfact(j2-m2)*dfact(j2+m2)));
  double S=0.0;
  for(int v=vmin;v<=vmax;++v){
    double sg = ((v+j2+m2)&1)? -1.0:1.0;
    S += sg*dfact(j2+j3+m1-v)*dfact(j1-m1+v)
        /(dfact(v)*dfact(j3-j1+j2-v)*dfact(j3+m3-v)*dfact(v+j1-j2-m3));
  }
  return C*S;
}

__device__ void qelem(int l,int r,int c,double &re,double &im){
  int m=r-l; double a=0.0,b=0.0; const double s=0.70710678118654752440;
  if(m<0){ if(c==l-m) a=s; else if(c==l+m) b=-s; }
  else if(m==0){ if(c==l) a=1.0; }
  else { double sg=(m&1)?-1.0:1.0; if(c==l+m) a=sg*s; else if(c==l-m) b=sg*s; }
  if(l==1){ double tt=a; a=b; b=-tt; }
  else if(l==2){ a=-a; b=-b; }
  re=a; im=b;
}

__device__ int probe_f32(const unsigned short* __restrict__ p, int nelem, int* scnt){
  if(threadIdx.x==0) *scnt=0;
  __syncthreads();
  int M = nelem < 4096 ? nelem : 4096;
  int c=0;
  for(int t=threadIdx.x;t<M;t+=blockDim.x){
    unsigned e=((unsigned)p[t]>>7)&0xFFu;
    if(e!=0u && (e<0x70u || e>0x8Eu)) ++c;
  }
  atomicAdd(scnt,c);
  __syncthreads();
  return (*scnt*8 > M) ? 1 : 0;
}

// ---------------- ONE prep kernel ----------------
// wpre[(p*3+tp)*2240 + w*140 + c] = pack_fp16(W[2c][w], W[2c+1][w])   (col c=u*8+vp)
__global__ void prep(const unsigned short* __restrict__ x,
                     const unsigned short* __restrict__ wq,
                     const unsigned short* __restrict__ wk,
                     const unsigned short* __restrict__ wv,
                     const unsigned short* __restrict__ wd,
                     int nx,int nw,int nd,
                     float* __restrict__ c3j, unsigned int* __restrict__ cgh,
                     unsigned int* __restrict__ wpre){
  const int p=blockIdx.x, tp=blockIdx.y;
  __shared__ double cg[125];
  __shared__ double outv[125];
  __shared__ double nrm;
  __shared__ int scnt;

  const unsigned short* ww=(tp==0)?wq:((tp==1)?wk:wv);
  const int f32 = probe_f32(ww,nw,&scnt);

  {
    unsigned int* dst=wpre+(size_t)(p*3+tp)*2240;
    for(int t=threadIdx.x;t<2048;t+=256){
      int w=t>>7, c=t&127;
      int i0=c*32+w, i1=i0+16;
      float f0,f1;
      if(f32){
        const float* wf=(const float*)ww+(size_t)p*4096;
        f0=wf[i0]; f1=wf[i1];
      }else{
        const unsigned short* wsp=ww+(size_t)p*4096;
        f0=bfu(wsp[i0]); f1=bfu(wsp[i1]);
      }
      dst[w*140+c]=(unsigned int)h16(f0)|((unsigned int)h16(f1)<<16);
    }
  }

  if(tp==0){
    int l1=g_l1[p], l2=g_l2[p], l3=g_l3[p];
    int d1=2*l1+1, d2=2*l2+1, d3=2*l3+1;
    int tot=d1*d2*d3;
    for(int t=threadIdx.x;t<tot;t+=256){
      int i=t/(d2*d3), k=(t/d3)%d2, n=t%d3;
      cg[t]=su2_cg(l1,i-l1,l2,k-l2,l3,n-l3);
    }
    __syncthreads();
    for(int t=threadIdx.x;t<tot;t+=256){
      int a=t/(d2*d3), b=(t/d3)%d2, c=t%d3;
      double sre=0.0;
      for(int i=0;i<d1;++i){ double q1r,q1i; qelem(l1,i,a,q1r,q1i);
        for(int k=0;k<d2;++k){ double q2r,q2i; qelem(l2,k,b,q2r,q2i);
          double pr=q1r*q2r-q1i*q2i, pi=q1r*q2i+q1i*q2r;
          for(int n=0;n<d3;++n){ double q3r,q3i; qelem(l3,n,c,q3r,q3i);
            sre += (pr*q3r + pi*q3i) * cg[(i*d2+k)*d3+n];
          }
        }
      }
      outv[t]=sre;
    }
    __syncthreads();
    if(threadIdx.x==0){
      double s=0.0; for(int t=0;t<tot;++t) s+=outv[t]*outv[t];
      nrm=sqrt(s);
    }
    __syncthreads();
    const float scl_[3]={0.03608439182435161f,0.05412658773652741f,0.06987712429686843f};
    float s=scl_[l3];
    for(int t=threadIdx.x;t<tot;t+=256){
      float val=(float)(outv[t]/nrm);
      c3j[g_coff[p]+t]=val;
      unsigned int h=(unsigned int)h16(val*s);
      cgh[g_coff[p]+t]=h|(h<<16);
    }
  }

  if(p==0 && tp==0){
    int xf=probe_f32(x,nx,&scnt);
    if(threadIdx.x==0) c3j[363]=(float)xf;
    int df=probe_f32(wd,nd,&scnt);
    if(threadIdx.x==0) c3j[367]=(float)df;
  }
}

// ---------------- fused stage 1, all-packed fp16 (coeffs via wave-uniform s_load from global) ----------------
// A[row=k*8+nn][col c=u*8+vp] halves(v=2vp,2vp+1) = sum_i x1[u,i]*( sum_j sC[ijk]*x2[v,j] )
template<int D1,int D2,int D3>
__device__ __forceinline__ void fusedAB(const unsigned int* __restrict__ sXp,
                                        const unsigned int* __restrict__ sXd,
                                        const unsigned int* __restrict__ cgp,
                                        unsigned int* __restrict__ sAu,
                                        int wave, int lane, int nvalid){
  constexpr int O1=(D1==1)?0:((D1==3)?16:64);
  constexpr int O2P=(D2==1)?0:((D2==3)?8:32);
  const int nn=lane>>3, vp=lane&7;
  if(nn>=nvalid) return;
  h2 x2p[D2];
  #pragma unroll
  for(int j=0;j<D2;++j) x2p[j]=__builtin_bit_cast(h2,sXp[nn*76+O2P+vp*D2+j]);
  const int u0=wave*2;
  h2 x1a[D1],x1b[D1];
  #pragma unroll
  for(int i=0;i<D1;++i){
    x1a[i]=__builtin_bit_cast(h2,sXd[nn*148+O1+u0*D1+i]);
    x1b[i]=__builtin_bit_cast(h2,sXd[nn*148+O1+(u0+1)*D1+i]);
  }
  h2 acc0[D3],acc1[D3];
  #pragma unroll
  for(int k=0;k<D3;++k){ acc0[k]=(h2){(_Float16)0.f,(_Float16)0.f}; acc1[k]=acc0[k]; }
  #pragma unroll
  for(int i=0;i<D1;++i){
    #pragma unroll
    for(int k=0;k<D3;++k){
      h2 ar=(h2){(_Float16)0.f,(_Float16)0.f};
      #pragma unroll
      for(int j=0;j<D2;++j)
        ar+=__builtin_bit_cast(h2,cgp[(i*D2+j)*D3+k])*x2p[j];
      acc0[k]+=x1a[i]*ar;
      acc1[k]+=x1b[i]*ar;
    }
  }
  #pragma unroll
  for(int k=0;k<D3;++k){
    sAu[(k*8+nn)*140+u0*8+vp]   =__builtin_bit_cast(unsigned int,acc0[k]);
    sAu[(k*8+nn)*140+u0*8+vp+8] =__builtin_bit_cast(unsigned int,acc1[k]);
  }
}

// ---------------- stage 2: MFMA, A from LDS, B prefetched in regs (compiler may sink) ----------------
template<int L3>
__device__ __forceinline__ void stage2_acc(const unsigned int* __restrict__ sAu,
                                           const unsigned int* __restrict__ wp_path,
                                           const uint4* __restrict__ bf,
                                           f32x4& a0, f32x4& a1,
                                           int n16, int quad, int wave){
  constexpr int P=(L3+1)*3;
  if(wave<P){
    int Mt=wave/3;
    const unsigned int* ap=sAu+(Mt*16+n16)*140+quad*4;
    f32x4 a=a0;
    #pragma unroll
    for(int ks=0;ks<8;++ks)
      a=__builtin_amdgcn_mfma_f32_16x16x32_f16(
          *reinterpret_cast<const half8*>(ap+ks*16),
          __builtin_bit_cast(half8,bf[ks]),a,0,0,0);
    a0=a;
  }
  if(L3==2 && wave==0){           // pid 8: tp=2, Mt=2
    const unsigned int* ap=sAu+(2*16+n16)*140+quad*4;
    const uint4* bp=(const uint4*)(wp_path+2*2240+n16*140+quad*4);
    uint4 b2[8];
    #pragma unroll
    for(int ks=0;ks<8;++ks) b2[ks]=bp[ks*4];
    f32x4 a=a1;
    #pragma unroll
    for(int ks=0;ks<8;++ks)
      a=__builtin_amdgcn_mfma_f32_16x16x32_f16(
          *reinterpret_cast<const half8*>(ap+ks*16),
          __builtin_bit_cast(half8,b2[ks]),a,0,0,0);
    a1=a;
  }
}

template<int L3>
__device__ __forceinline__ void stage2_out(const f32x4& a0, const f32x4& a1,
                                           float* __restrict__ sO,
                                           int n16, int quad, int wave){
  constexpr int D3=2*L3+1;
  constexpr int OO=(L3==0)?0:((L3==1)?16:64);
  constexpr int P=(L3+1)*3;
  if(wave<P){
    int tp=wave%3, Mt=wave/3;
    #pragma unroll
    for(int reg=0;reg<4;++reg){
      int row=Mt*16+quad*4+reg;
      int k=row>>3, node=row&7;
      if(k<D3) sO[node*440+tp*144+OO+n16*D3+k]=a0[reg];
    }
  }
  if(L3==2 && wave==0){
    #pragma unroll
    for(int reg=0;reg<4;++reg){
      int row=32+quad*4+reg;
      int k=row>>3, node=row&7;
      if(k<D3) sO[node*440+2*144+OO+n16*D3+k]=a1[reg];
    }
  }
}

__global__ __launch_bounds__(512,6) void tfn_main(
    const unsigned short* __restrict__ xin,
    const unsigned int* __restrict__ wpre,
    const unsigned int* __restrict__ cgh,
    const unsigned short* __restrict__ wd,
    const float* __restrict__ c3j,
    unsigned short* __restrict__ outp, int N)
{
  __shared__ __align__(16) unsigned int sAu[48*140];  // fp16 A, row stride 140 dwords
  __shared__ float sO[NN*440];                        // also staging scratch for fp32 x
  __shared__ __align__(8) unsigned int sXp[NN*76];    // (v,v+1)-pair packs per (vp,j)
  __shared__ __align__(8) unsigned int sXd[NN*148];   // (x,x) dup packs per feature
  __shared__ float sWd[768];

  const int tid=threadIdx.x;
  const int wave=tid>>6, lane=tid&63;
  const int n16=lane&15, quad=lane>>4;
  const int node0=blockIdx.x*NN;
  const int nvalid=(N-node0)<NN?(N-node0):NN;

  const int xf32 = c3j[363]!=0.0f;
  const int df32 = c3j[367]!=0.0f;

  // ---- stage x into fp32 scratch (sO reused; consumed before first stage2_out) ----
  float* scratch=sO;
  if(!xf32){
    for(int t=tid;t<NN*36;t+=512){
      int nn=t/36, w4=t%36;
      if(nn<nvalid){
        uint2 u=((const uint2*)(xin+(size_t)(node0+nn)*144))[w4];
        float* dst=&scratch[nn*144+w4*4];
        dst[0]=bfu(u.x&0xffffu); dst[1]=bfu(u.x>>16);
        dst[2]=bfu(u.y&0xffffu); dst[3]=bfu(u.y>>16);
      }
    }
  }else{
    const float* xf=(const float*)xin;
    for(int t=tid;t<NN*144;t+=512){
      int nn=t/144, f=t%144;
      if(nn<nvalid) scratch[nn*144+f]=xf[(size_t)(node0+nn)*144+f];
    }
  }
  if(!df32){ for(int t=tid;t<768;t+=512) sWd[t]=bfu((unsigned int)wd[t]); }
  else     { const float* wdf=(const float*)wd; for(int t=tid;t<768;t+=512) sWd[t]=wdf[t]; }
  __syncthreads();

  // ---- build packed fp16 x images ----
  for(int t=tid;t<NN*144;t+=512){
    int nn=t/144, f=t-nn*144;
    unsigned int h=(unsigned int)h16(scratch[t]);
    sXd[nn*148+f]=h|(h<<16);
  }
  for(int t=tid;t<NN*72;t+=512){
    int nn=t/72, g=t-nn*72;
    int fa,fb;
    if(g<8){ fa=2*g; fb=fa+1; }
    else if(g<32){ int gg=g-8; int vp=gg/3, j=gg-3*vp; fa=16+(2*vp)*3+j; fb=fa+3; }
    else { int gg=g-32; int vp=gg/5, j=gg-5*vp; fa=64+(2*vp)*5+j; fb=fa+5; }
    sXp[nn*76+g]=(unsigned int)h16(scratch[nn*144+fa])|((unsigned int)h16(scratch[nn*144+fb])<<16);
  }
  __syncthreads();

  // one path step: prefetch B, fusedAB, barrier, MFMA, barrier
  #define PATH_STEP(P_,D1_,D2_,D3_) { \
    const int PT=((D3_-1)/2+1)*3; \
    uint4 bf[8]; \
    if(wave<PT){ \
      const uint4* bp=(const uint4*)(wpre+(size_t)P_*6720+(wave%3)*2240+n16*140+quad*4); \
      bf[0]=bp[0];  bf[1]=bp[4];  bf[2]=bp[8];  bf[3]=bp[12]; \
      bf[4]=bp[16]; bf[5]=bp[20]; bf[6]=bp[24]; bf[7]=bp[28]; \
    } \
    fusedAB<D1_,D2_,D3_>(sXp,sXd,cgh+g_coff[P_],sAu,wave,lane,nvalid); \
    __syncthreads(); \
    stage2_acc<(D3_-1)/2>(sAu,wpre+(size_t)P_*6720,bf,a0,a1,n16,quad,wave); \
    __syncthreads(); }

  { // group l3=0: paths 0,1,2
    f32x4 a0={0.f,0.f,0.f,0.f}, a1={0.f,0.f,0.f,0.f};
    PATH_STEP(0,1,1,1)
    PATH_STEP(1,3,3,1)
    PATH_STEP(2,5,5,1)
    stage2_out<0>(a0,a1,sO,n16,quad,wave);
  }
  { // group l3=1: paths 3,4,5,6
    f32x4 a0={0.f,0.f,0.f,0.f}, a1={0.f,0.f,0.f,0.f};
    PATH_STEP(3,1,3,3)
    PATH_STEP(4,3,1,3)
    PATH_STEP(5,3,5,3)
    PATH_STEP(6,5,3,3)
    stage2_out<1>(a0,a1,sO,n16,quad,wave);
  }
  { // group l3=2: paths 7,8,9,10
    f32x4 a0={0.f,0.f,0.f,0.f}, a1={0.f,0.f,0.f,0.f};
    PATH_STEP(7,1,5,5)
    PATH_STEP(8,3,3,5)
    PATH_STEP(9,5,1,5)
    PATH_STEP(10,5,5,5)
    stage2_out<2>(a0,a1,sO,n16,quad,wave);
  }
  #undef PATH_STEP
  __syncthreads();

  // ---- epilogue: dot via C(l,l,0)=c_l*I; attention; elu; store ----
  {
    int node=wave;
    if(node<nvalid){
      const float c0=c3j[0], c1=c3j[1], c2=c3j[10];
      const float* qv=sO+node*440;
      const float* kv=qv+144;
      const int v=lane&15, ug=lane>>4;
      float k0=kv[v];
      float k1[3],k2[5];
      #pragma unroll
      for(int j=0;j<3;++j) k1[j]=kv[16+v*3+j];
      #pragma unroll
      for(int m=0;m<5;++m) k2[m]=kv[64+v*5+m];
      float part=0.f;
      #pragma unroll
      for(int t=0;t<4;++t){
        int u=ug+4*t;
        float d0=qv[u]*k0;
        float d1=0.f;
        #pragma unroll
        for(int j=0;j<3;++j) d1+=qv[16+u*3+j]*k1[j];
        float d2=0.f;
        #pragma unroll
        for(int m=0;m<5;++m) d2+=qv[64+u*5+m]*k2[m];
        part+=sWd[u*16+v]*(c0*d0)+sWd[256+u*16+v]*(c1*d1)+sWd[512+u*16+v]*(c2*d2);
      }
      #pragma unroll
      for(int off=1;off<64;off<<=1) part+=__shfl_xor(part,off,64);
      float dd=part*0.03608439182435161f;   // * sqrt(1/768)
      float ex=dd*(1.0f/12.0f);             // / sqrt(144)
      ex=fminf(fmaxf(ex,-80.f),80.f);
      float e=expf(ex);
      float attn=e/(e+1e-10f);
      const float* vv=sO+node*440+288;
      if(!xf32){
        unsigned short* ob=outp+(size_t)(node0+node)*144;
        for(int f=lane;f<144;f+=64){
          float val=attn*vv[f];
          float r=(val>0.f)?val:expm1f(val);
          ob[f]=(unsigned short)rne16(r);
        }
      }else{
        float* ob=(float*)outp+(size_t)(node0+node)*144;
        for(int f=lane;f<144;f+=64){
          float val=attn*vv[f];
          ob[f]=(val>0.f)?val:expm1f(val);
        }
      }
    }
  }
}

extern "C" void kernel_launch(void* const* d_in, const int* in_sizes, int n_in,
                              void* d_out, int out_size, void* d_ws, size_t ws_size,
                              hipStream_t stream){
  (void)n_in; (void)out_size; (void)ws_size;
  const unsigned short* x =(const unsigned short*)d_in[0];
  const unsigned short* wq=(const unsigned short*)d_in[4];
  const unsigned short* wk=(const unsigned short*)d_in[5];
  const unsigned short* wv=(const unsigned short*)d_in[6];
  const unsigned short* wd=(const unsigned short*)d_in[7];
  float* c3j=(float*)d_ws;                                 // [0..362] w3j, [363..367] flags
  unsigned int* cgh=(unsigned int*)d_ws+1024;              // packed scale*C fp16 pairs (363)
  unsigned int* wpre=(unsigned int*)d_ws+2048;             // 11*3*2240 packed fp16 W^T
  int N=in_sizes[0]/144;
  prep<<<dim3(NP,3),dim3(256),0,stream>>>(x,wq,wk,wv,wd,
      in_sizes[0],in_sizes[4],in_sizes[7],c3j,cgh,wpre);
  int nb=(N+NN-1)/NN;
  tfn_main<<<dim3(nb),dim3(512),0,stream>>>(x,wpre,cgh,wd,c3j,(unsigned short*)d_out,N);
}